// Round 4
// baseline (998.809 us; speedup 1.0000x reference)
//
#include <hip/hip_runtime.h>
#include <math.h>

#define NB 512
#define ROWW 585            // 15*39
#define PLANE 5265          // 9*15*39
#define IN_PER_B 57915      // 11*9*15*39
#define OUT_SP 30303        // 9*7*13*37
#define SEG 2340            // fixed LDS k0-plane stride: 4 d1-rows * 585
#define NTAP 81

// Block = (batch b, o0 in [0,9), o1-tile). T1 = o1-tile height (2,2,2,1 covering 7).
// LDS slab: x[k0 in 0..2][d1_local in 0..T1+1][15*39], fixed stride SEG so all
// tap offsets are compile-time immediates on ds_read.
template<int T1, int NS>
__global__ __launch_bounds__(256, 2) void conv_fused(
    const float* __restrict__ x_re, const float* __restrict__ x_im,
    const float* __restrict__ w_re, const float* __restrict__ w_im,
    const float* __restrict__ b_re, const float* __restrict__ b_im,
    const float* __restrict__ lw, float* __restrict__ batch_acc)
{
    __shared__ float sxr[3*SEG];                 // 7020 f32 = 28.1 KB
    __shared__ float sxi[3*SEG];                 // 28.1 KB
    __shared__ alignas(16) float sw[NTAP][8];    // [tap][wr0..3, wi0..3]
    __shared__ float sb[8];
    __shared__ float red[4];

    int b, o0, o1b;
    if (T1 == 2) {
        const int blk = blockIdx.x;
        b = blk / 27;
        const int r = blk - b*27;
        o0 = r / 3;
        o1b = (r - o0*3) * 2;   // 0,2,4
    } else {
        const int blk = blockIdx.x;
        b = blk / 9;
        o0 = blk - b*9;
        o1b = 6;
    }
    const int tid = threadIdx.x;

    // stage weights: sw[t][c] = w_re[c][t], sw[t][4+c] = w_im[c][t]
    for (int i = tid; i < NTAP*4; i += 256) {
        const int c = i / NTAP, t = i - c*NTAP;
        sw[t][c]   = w_re[i];
        sw[t][4+c] = w_im[i];
    }
    if (tid < 4) { sb[tid] = b_re[tid]; sb[4+tid] = b_im[tid]; }

    // stage input slab (contiguous per k0-plane)
    const size_t ibase = (size_t)b*IN_PER_B + (size_t)o0*PLANE + (size_t)o1b*ROWW;
    const int cpy = (T1+2)*ROWW;
    for (int k0 = 0; k0 < 3; ++k0) {
        const float* gr = x_re + ibase + (size_t)k0*PLANE;
        const float* gi = x_im + ibase + (size_t)k0*PLANE;
        float* dr = sxr + k0*SEG;
        float* di = sxi + k0*SEG;
        for (int i = tid; i < cpy; i += 256) { dr[i] = gr[i]; di[i] = gi[i]; }
    }
    __syncthreads();

    // per-thread position slots
    const int npos = T1*481;   // T1*13*37
    int pb[NS]; int fb[NS]; bool act[NS];
    #pragma unroll
    for (int s = 0; s < NS; ++s) {
        const int pos = tid + s*256;
        act[s] = pos < npos;
        const int p = act[s] ? pos : 0;
        const int o1l = p / 481;
        const int rr  = p - o1l*481;
        const int o2  = rr / 37;
        const int o3  = rr - o2*37;
        pb[s] = o1l*ROWW + o2*39 + o3;
        fb[s] = ((o0*7 + o1b + o1l)*13 + o2)*37 + o3;
    }

    float ar[NS][4], ai[NS][4];
    #pragma unroll
    for (int s = 0; s < NS; ++s)
        #pragma unroll
        for (int c = 0; c < 4; ++c) { ar[s][c] = sb[c]; ai[s][c] = sb[4+c]; }

    // main tap loop: weights broadcast once per tap, reused across NS slots
    for (int k0 = 0; k0 < 3; ++k0) {
        for (int k1 = 0; k1 < 3; ++k1) {
            const int rowoff = k0*SEG + k1*ROWW;
            const int tw = (k0*3 + k1)*9;
            #pragma unroll
            for (int k2 = 0; k2 < 3; ++k2) {
                #pragma unroll
                for (int k3 = 0; k3 < 3; ++k3) {
                    const float4 wr4 = *(const float4*)(&sw[tw + k2*3 + k3][0]);
                    const float4 wi4 = *(const float4*)(&sw[tw + k2*3 + k3][4]);
                    #pragma unroll
                    for (int s = 0; s < NS; ++s) {
                        const int idx = pb[s] + rowoff + k2*39 + k3;
                        const float xr = sxr[idx];
                        const float xi = sxi[idx];
                        ar[s][0] = fmaf(xr, wr4.x, ar[s][0]);
                        ar[s][1] = fmaf(xr, wr4.y, ar[s][1]);
                        ar[s][2] = fmaf(xr, wr4.z, ar[s][2]);
                        ar[s][3] = fmaf(xr, wr4.w, ar[s][3]);
                        ar[s][0] = fmaf(-xi, wi4.x, ar[s][0]);
                        ar[s][1] = fmaf(-xi, wi4.y, ar[s][1]);
                        ar[s][2] = fmaf(-xi, wi4.z, ar[s][2]);
                        ar[s][3] = fmaf(-xi, wi4.w, ar[s][3]);
                        ai[s][0] = fmaf(xr, wi4.x, ai[s][0]);
                        ai[s][1] = fmaf(xr, wi4.y, ai[s][1]);
                        ai[s][2] = fmaf(xr, wi4.z, ai[s][2]);
                        ai[s][3] = fmaf(xr, wi4.w, ai[s][3]);
                        ai[s][0] = fmaf(xi, wr4.x, ai[s][0]);
                        ai[s][1] = fmaf(xi, wr4.y, ai[s][1]);
                        ai[s][2] = fmaf(xi, wr4.z, ai[s][2]);
                        ai[s][3] = fmaf(xi, wr4.w, ai[s][3]);
                    }
                }
            }
        }
    }

    // epilogue: bias already in acc; CReLU -> modulus -> dot with lw
    float partial = 0.f;
    #pragma unroll
    for (int s = 0; s < NS; ++s) {
        if (act[s]) {
            #pragma unroll
            for (int c = 0; c < 4; ++c) {
                const float re = fmaxf(ar[s][c], 0.f);
                const float im = fmaxf(ai[s][c], 0.f);
                const float mag = sqrtf(fmaf(re, re, im*im));
                partial += mag * lw[c*OUT_SP + fb[s]];
            }
        }
    }

    // wave reduce (64 lanes) then block reduce, one atomic per block
    #pragma unroll
    for (int off = 32; off > 0; off >>= 1)
        partial += __shfl_down(partial, off, 64);
    if ((tid & 63) == 0) red[tid >> 6] = partial;
    __syncthreads();
    if (tid == 0) atomicAdd(&batch_acc[b], red[0] + red[1] + red[2] + red[3]);
}

__global__ void finalize_k(const float* __restrict__ acc, const float* __restrict__ lb,
                           float* __restrict__ out) {
    const int i = blockIdx.x * blockDim.x + threadIdx.x;
    if (i < NB) out[i] = 1.f / (1.f + expf(-(acc[i] + lb[0])));
}

extern "C" void kernel_launch(void* const* d_in, const int* in_sizes, int n_in,
                              void* d_out, int out_size, void* d_ws, size_t ws_size,
                              hipStream_t stream) {
    const float* x_re = (const float*)d_in[0];
    const float* x_im = (const float*)d_in[1];
    const float* w_re = (const float*)d_in[2];
    const float* w_im = (const float*)d_in[3];
    const float* b_re = (const float*)d_in[4];
    const float* b_im = (const float*)d_in[5];
    const float* lw   = (const float*)d_in[6];
    const float* lb   = (const float*)d_in[7];
    float* acc = (float*)d_ws;

    hipMemsetAsync(acc, 0, NB*sizeof(float), stream);

    // o1 tiles {0,1},{2,3},{4,5} -> T1=2 (4 slots); tile {6} -> T1=1 (2 slots)
    hipLaunchKernelGGL((conv_fused<2,4>), dim3(NB*27), dim3(256), 0, stream,
                       x_re, x_im, w_re, w_im, b_re, b_im, lw, acc);
    hipLaunchKernelGGL((conv_fused<1,2>), dim3(NB*9), dim3(256), 0, stream,
                       x_re, x_im, w_re, w_im, b_re, b_im, lw, acc);
    finalize_k<<<dim3(2), dim3(256), 0, stream>>>(acc, lb, (float*)d_out);
}

// Round 5
// 772.130 us; speedup vs baseline: 1.2936x; 1.2936x over previous
//
#include <hip/hip_runtime.h>
#include <math.h>

#define NB 512
#define ROWW 585            // 15*39
#define PLANE 5265          // 9*15*39
#define IN_PER_B 57915      // 11*9*15*39
#define OUT_SP 30303        // 9*7*13*37
#define SEG 2340            // fixed LDS k0-plane stride: 4 d1-rows * 585 (u32 pairs)
#define NTAP 81

__device__ __forceinline__ unsigned bf16rne(float f) {
    unsigned u = __float_as_uint(f);
    return (u + 0x7fffu + ((u >> 16) & 1u)) >> 16;
}

// Block = (batch b, o0 in [0,9), o1-tile t in [0,4)). Tiles {0,1},{2,3},{4,5},{6}.
// LDS slab: packed bf16 (xr,xi) pairs, [k0 in 0..2][d1_local][15*39], stride SEG.
// bf16 halves LDS vs f32 re+im -> 4 blocks/CU (was 2) to fix latency-boundedness.
__global__ __launch_bounds__(256, 4) void conv_fused(
    const float* __restrict__ x_re, const float* __restrict__ x_im,
    const float* __restrict__ w_re, const float* __restrict__ w_im,
    const float* __restrict__ b_re, const float* __restrict__ b_im,
    const float* __restrict__ lw, float* __restrict__ batch_acc)
{
    __shared__ unsigned sx[3*SEG];               // 7020 u32 = 28.1 KB (bf16 xr|xi pairs)
    __shared__ alignas(16) float sw[NTAP][8];    // [tap][wr0..3, wi0..3]
    __shared__ float sb[8];
    __shared__ float red[4];

    const int blk = blockIdx.x;
    const int b = blk / 36;
    const int r = blk - b*36;
    const int o0 = r >> 2;
    const int t  = r & 3;
    const int o1b = t*2;                 // 0,2,4,6
    const int T1 = (t == 3) ? 1 : 2;
    const int tid = threadIdx.x;

    // stage weights: sw[t][c] = w_re[c][t], sw[t][4+c] = w_im[c][t]
    for (int i = tid; i < NTAP*4; i += 256) {
        const int c = i / NTAP, tp = i - c*NTAP;
        sw[tp][c]   = w_re[i];
        sw[tp][4+c] = w_im[i];
    }
    if (tid < 4) { sb[tid] = b_re[tid]; sb[4+tid] = b_im[tid]; }

    // stage input slab as packed bf16 pairs (contiguous per k0-plane)
    const size_t ibase = (size_t)b*IN_PER_B + (size_t)o0*PLANE + (size_t)o1b*ROWW;
    const int cpy = (T1+2)*ROWW;
    for (int k0 = 0; k0 < 3; ++k0) {
        const float* gr = x_re + ibase + (size_t)k0*PLANE;
        const float* gi = x_im + ibase + (size_t)k0*PLANE;
        unsigned* ds = sx + k0*SEG;
        for (int i = tid; i < cpy; i += 256)
            ds[i] = (bf16rne(gi[i]) << 16) | bf16rne(gr[i]);
    }
    __syncthreads();

    // per-thread position slots
    const int npos = T1*481;   // T1*13*37
    int pb[4]; int fb[4]; bool act[4];
    #pragma unroll
    for (int s = 0; s < 4; ++s) {
        const int pos = tid + s*256;
        act[s] = pos < npos;
        const int p = act[s] ? pos : 0;
        const int o1l = p / 481;
        const int rr  = p - o1l*481;
        const int o2  = rr / 37;
        const int o3  = rr - o2*37;
        pb[s] = o1l*ROWW + o2*39 + o3;
        fb[s] = ((o0*7 + o1b + o1l)*13 + o2)*37 + o3;
    }

    float ar[4][4], ai[4][4];
    #pragma unroll
    for (int s = 0; s < 4; ++s)
        #pragma unroll
        for (int c = 0; c < 4; ++c) { ar[s][c] = sb[c]; ai[s][c] = sb[4+c]; }

    // main tap loop: weight float4 broadcast per tap, input pair unpack feeds 16 fma
    for (int k0 = 0; k0 < 3; ++k0) {
        for (int k1 = 0; k1 < 3; ++k1) {
            const int rowoff = k0*SEG + k1*ROWW;
            const int tw = (k0*3 + k1)*9;
            #pragma unroll
            for (int k2 = 0; k2 < 3; ++k2) {
                #pragma unroll
                for (int k3 = 0; k3 < 3; ++k3) {
                    const float4 wr4 = *(const float4*)(&sw[tw + k2*3 + k3][0]);
                    const float4 wi4 = *(const float4*)(&sw[tw + k2*3 + k3][4]);
                    #pragma unroll
                    for (int s = 0; s < 4; ++s) {
                        const unsigned pr = sx[pb[s] + rowoff + k2*39 + k3];
                        const float xr = __uint_as_float(pr << 16);
                        const float xi = __uint_as_float(pr & 0xffff0000u);
                        ar[s][0] = fmaf(xr, wr4.x, ar[s][0]);
                        ar[s][1] = fmaf(xr, wr4.y, ar[s][1]);
                        ar[s][2] = fmaf(xr, wr4.z, ar[s][2]);
                        ar[s][3] = fmaf(xr, wr4.w, ar[s][3]);
                        ar[s][0] = fmaf(-xi, wi4.x, ar[s][0]);
                        ar[s][1] = fmaf(-xi, wi4.y, ar[s][1]);
                        ar[s][2] = fmaf(-xi, wi4.z, ar[s][2]);
                        ar[s][3] = fmaf(-xi, wi4.w, ar[s][3]);
                        ai[s][0] = fmaf(xr, wi4.x, ai[s][0]);
                        ai[s][1] = fmaf(xr, wi4.y, ai[s][1]);
                        ai[s][2] = fmaf(xr, wi4.z, ai[s][2]);
                        ai[s][3] = fmaf(xr, wi4.w, ai[s][3]);
                        ai[s][0] = fmaf(xi, wr4.x, ai[s][0]);
                        ai[s][1] = fmaf(xi, wr4.y, ai[s][1]);
                        ai[s][2] = fmaf(xi, wr4.z, ai[s][2]);
                        ai[s][3] = fmaf(xi, wr4.w, ai[s][3]);
                    }
                }
            }
        }
    }

    // epilogue: bias already in acc; CReLU -> modulus -> dot with lw
    float partial = 0.f;
    #pragma unroll
    for (int s = 0; s < 4; ++s) {
        if (act[s]) {
            #pragma unroll
            for (int c = 0; c < 4; ++c) {
                const float re = fmaxf(ar[s][c], 0.f);
                const float im = fmaxf(ai[s][c], 0.f);
                const float mag = sqrtf(fmaf(re, re, im*im));
                partial += mag * lw[c*OUT_SP + fb[s]];
            }
        }
    }

    // wave reduce (64 lanes) then block reduce, one atomic per block
    #pragma unroll
    for (int off = 32; off > 0; off >>= 1)
        partial += __shfl_down(partial, off, 64);
    if ((tid & 63) == 0) red[tid >> 6] = partial;
    __syncthreads();
    if (tid == 0) atomicAdd(&batch_acc[b], red[0] + red[1] + red[2] + red[3]);
}

__global__ void finalize_k(const float* __restrict__ acc, const float* __restrict__ lb,
                           float* __restrict__ out) {
    const int i = blockIdx.x * blockDim.x + threadIdx.x;
    if (i < NB) out[i] = 1.f / (1.f + expf(-(acc[i] + lb[0])));
}

extern "C" void kernel_launch(void* const* d_in, const int* in_sizes, int n_in,
                              void* d_out, int out_size, void* d_ws, size_t ws_size,
                              hipStream_t stream) {
    const float* x_re = (const float*)d_in[0];
    const float* x_im = (const float*)d_in[1];
    const float* w_re = (const float*)d_in[2];
    const float* w_im = (const float*)d_in[3];
    const float* b_re = (const float*)d_in[4];
    const float* b_im = (const float*)d_in[5];
    const float* lw   = (const float*)d_in[6];
    const float* lb   = (const float*)d_in[7];
    float* acc = (float*)d_ws;

    hipMemsetAsync(acc, 0, NB*sizeof(float), stream);

    // single launch: 4 o1-tiles per (b, o0); tile 3 is the ragged {6} tile
    hipLaunchKernelGGL(conv_fused, dim3(NB*36), dim3(256), 0, stream,
                       x_re, x_im, w_re, w_im, b_re, b_im, lw, acc);
    finalize_k<<<dim3(2), dim3(256), 0, stream>>>(acc, lb, (float*)d_out);
}

// Round 7
// 626.160 us; speedup vs baseline: 1.5951x; 1.2331x over previous
//
#include <hip/hip_runtime.h>
#include <math.h>

#define NB 512
#define ROWW 585            // 15*39
#define PLANE 5265          // 9*15*39
#define IN_PER_B 57915      // 11*9*15*39
#define OUT_SP 30303        // 9*7*13*37
#define SEG 2340            // LDS k0-plane stride: 4 d1-rows * 585 (u32 pairs)
#define NTAP 81

typedef __attribute__((ext_vector_type(8))) short short8;   // 8 bf16 = 4 VGPR
typedef __attribute__((ext_vector_type(4))) float f32x4;

__device__ __forceinline__ unsigned bf16rne(float f) {
    unsigned u = __float_as_uint(f);
    return (u + 0x7fffu + ((u >> 16) & 1u)) >> 16;
}
__device__ __forceinline__ short bf16s(float f) { return (short)bf16rne(f); }

// Complex 4D conv as MFMA GEMM: C[8][16pos] = A[8][K]*B[K][16pos].
// K = 28 (k0,k1,k2)-rows x 4 slots{k3=0,1,2,pad} x {xr,xi} = 224 = 7 MFMA chunks.
// B-fragment per lane = 3 u32 (packed xr|xi bf16 pairs) from the slab at
// pb + rowoff; pad slot = dup of u32[2], zero-weighted in A.
// C/D layout (m89-verified): col=lane&15 (position), row=(lane>>4)*4+reg.
__global__ __launch_bounds__(256, 4) void conv_mfma(
    const float* __restrict__ x_re, const float* __restrict__ x_im,
    const float* __restrict__ w_re, const float* __restrict__ w_im,
    const float* __restrict__ b_re, const float* __restrict__ b_im,
    const float* __restrict__ lw, float* __restrict__ batch_acc)
{
    __shared__ unsigned sx[3*SEG];   // 28.1 KB packed bf16 (xr|xi) pairs
    __shared__ float red[4];

    const int blk = blockIdx.x;
    const int b  = blk / 36;
    const int r  = blk - b*36;
    const int o0 = r >> 2;
    const int tt = r & 3;
    const int o1b = tt*2;                 // 0,2,4,6
    const int T1 = (tt == 3) ? 1 : 2;
    const int tid = threadIdx.x;

    // ---- stage input slab as packed bf16 pairs (contiguous per k0-plane) ----
    const size_t ibase = (size_t)b*IN_PER_B + (size_t)o0*PLANE + (size_t)o1b*ROWW;
    const int cpy = (T1+2)*ROWW;
    for (int k0 = 0; k0 < 3; ++k0) {
        const float* gr = x_re + ibase + (size_t)k0*PLANE;
        const float* gi = x_im + ibase + (size_t)k0*PLANE;
        unsigned* ds = sx + k0*SEG;
        for (int i = tid; i < cpy; i += 256)
            ds[i] = (bf16rne(gi[i]) << 16) | bf16rne(gr[i]);
    }

    // ---- per-lane A-fragments (weights) + row offsets, once per block ----
    const int lane = tid & 63;
    const int m  = lane & 15;       // A-row / B-col role
    const int kb = lane >> 4;       // K-block role
    short8 afrag[7];
    int rowoff[7];
    #pragma unroll
    for (int c = 0; c < 7; ++c) {
        const int row = 4*c + kb;                  // (k0,k1,k2) row index, 0..27
        const int rc = (row < 27) ? row : 0;       // address clamp for pad row
        rowoff[c] = (rc/9)*SEG + ((rc%9)/3)*ROWW + (rc%3)*39;
        short8 a = {0,0,0,0,0,0,0,0};
        if (row < 27 && m < 8) {
            const int ch = m & 3;
            const bool isIm = m >= 4;
            #pragma unroll
            for (int j = 0; j < 3; ++j) {
                const int tp = row*3 + j;          // tap = row*3 + k3
                const float wr = w_re[ch*NTAP + tp];
                const float wi = w_im[ch*NTAP + tp];
                a[2*j]   = bf16s(isIm ? wi : wr);  // multiplies xr
                a[2*j+1] = bf16s(isIm ? wr : -wi); // multiplies xi
            }
        }
        afrag[c] = a;
    }
    const float brv[4] = {b_re[0], b_re[1], b_re[2], b_re[3]};
    const float biv[4] = {b_im[0], b_im[1], b_im[2], b_im[3]};
    __syncthreads();

    // ---- tile loop: each wave owns every 4th 16-position tile ----
    const int npos = T1*481;                 // T1*13*37
    const int ntiles = (npos + 15) >> 4;
    const int wave = tid >> 6;
    float partial = 0.f;

    for (int tile = wave; tile < ntiles; tile += 4) {
        const int n = tile*16 + m;           // this lane's column position
        const bool ok = n < npos;
        const int p = ok ? n : 0;
        const int o1l = p / 481;
        const int r2  = p - o1l*481;
        const int o2  = r2 / 37;
        const int o3  = r2 - o2*37;
        const int pb  = o1l*ROWW + o2*39 + o3;

        f32x4 acc = {0.f, 0.f, 0.f, 0.f};
        #pragma unroll
        for (int c = 0; c < 7; ++c) {
            const unsigned* s = sx + pb + rowoff[c];
            union { unsigned u[4]; short8 s8; } bu;
            bu.u[0] = s[0];
            bu.u[1] = s[1];
            bu.u[2] = s[2];
            bu.u[3] = bu.u[2];               // pad slot, zero-weighted
            acc = __builtin_amdgcn_mfma_f32_16x16x32_bf16(afrag[c], bu.s8, acc, 0, 0, 0);
        }

        // epilogue: lanes 0-15 hold re rows (0-3), lanes 16-31 hold im rows (4-7)
        float imv[4];
        #pragma unroll
        for (int c2 = 0; c2 < 4; ++c2) imv[c2] = __shfl_down(acc[c2], 16, 64);
        if (lane < 16 && ok) {
            const int fb = ((o0*7 + o1b + o1l)*13 + o2)*37 + o3;
            #pragma unroll
            for (int c2 = 0; c2 < 4; ++c2) {
                const float re = fmaxf(acc[c2] + brv[c2], 0.f);
                const float im = fmaxf(imv[c2] + biv[c2], 0.f);
                const float mag = sqrtf(fmaf(re, re, im*im));
                partial += mag * lw[c2*OUT_SP + fb];
            }
        }
    }

    // wave reduce then block reduce, one atomic per block
    #pragma unroll
    for (int off = 32; off > 0; off >>= 1)
        partial += __shfl_down(partial, off, 64);
    if ((tid & 63) == 0) red[tid >> 6] = partial;
    __syncthreads();
    if (tid == 0) atomicAdd(&batch_acc[b], red[0] + red[1] + red[2] + red[3]);
}

__global__ void finalize_k(const float* __restrict__ acc, const float* __restrict__ lb,
                           float* __restrict__ out) {
    const int i = blockIdx.x * blockDim.x + threadIdx.x;
    if (i < NB) out[i] = 1.f / (1.f + expf(-(acc[i] + lb[0])));
}

extern "C" void kernel_launch(void* const* d_in, const int* in_sizes, int n_in,
                              void* d_out, int out_size, void* d_ws, size_t ws_size,
                              hipStream_t stream) {
    const float* x_re = (const float*)d_in[0];
    const float* x_im = (const float*)d_in[1];
    const float* w_re = (const float*)d_in[2];
    const float* w_im = (const float*)d_in[3];
    const float* b_re = (const float*)d_in[4];
    const float* b_im = (const float*)d_in[5];
    const float* lw   = (const float*)d_in[6];
    const float* lb   = (const float*)d_in[7];
    float* acc = (float*)d_ws;

    hipMemsetAsync(acc, 0, NB*sizeof(float), stream);

    // single launch: 4 o1-tiles per (b, o0); tile 3 is the ragged {6} tile
    hipLaunchKernelGGL(conv_mfma, dim3(NB*36), dim3(256), 0, stream,
                       x_re, x_im, w_re, w_im, b_re, b_im, lw, acc);
    finalize_k<<<dim3(2), dim3(256), 0, stream>>>(acc, lb, (float*)d_out);
}

// Round 8
// 554.498 us; speedup vs baseline: 1.8013x; 1.1292x over previous
//
#include <hip/hip_runtime.h>
#include <hip/hip_bf16.h>
#include <math.h>

#define NB 512
#define ROWW 585            // 15*39
#define PLANE 5265          // 9*15*39
#define IN_PER_B 57915      // 11*9*15*39
#define OUT_SP 30303        // 9*7*13*37
#define SEG 2340            // LDS k0-plane stride: 4 d1-rows * 585 (u32 pairs)
#define POSPP 481           // 13*37 positions per o1-row

typedef __attribute__((ext_vector_type(8))) short short8;   // 8 bf16 = 4 VGPR
typedef __attribute__((ext_vector_type(4))) float f32x4;

__device__ __forceinline__ unsigned bf16rne(float f) {
    unsigned u = __float_as_uint(f);
    return (u + 0x7fffu + ((u >> 16) & 1u)) >> 16;
}
__device__ __forceinline__ short bf16s(float f) { return (short)bf16rne(f); }

__device__ __forceinline__ unsigned packpair(float re, float im) {
    __hip_bfloat162 h = __float22bfloat162_rn(make_float2(re, im));  // v_cvt_pk
    union { __hip_bfloat162 h2; unsigned u; } cv; cv.h2 = h;
    return cv.u;   // low16 = re, high16 = im
}

// Complex 4D conv as MFMA GEMM, DUAL o1-row per tile:
// C[16][16pos]: rows 0-3 re(o1l=0) ch0-3, 4-7 im(o1l=0), 8-11 re(o1l=1), 12-15 im(o1l=1).
// K = 36 rows (k0 x d1local(4) x k2) x 4 slots{k3=0,1,2,pad} x {xr,xi} = 288 = 9 MFMA.
// A rows 8-15 = weights with k1 = d1local-1 (one-row shift) -> o1l+1 output free.
// Fragment roles HW-verified by R7 pass: A row=lane&15 k-chunk=lane>>4;
// B col=lane&15; C col=lane&15 row=(lane>>4)*4+reg.
__global__ __launch_bounds__(256, 4) void conv_mfma(
    const float* __restrict__ x_re, const float* __restrict__ x_im,
    const float* __restrict__ w_re, const float* __restrict__ w_im,
    const float* __restrict__ b_re, const float* __restrict__ b_im,
    const float* __restrict__ lw, float* __restrict__ partials)
{
    __shared__ unsigned sx[3*SEG];   // 28.1 KB packed bf16 (re|im) pairs
    __shared__ float red[4];

    const int blk = blockIdx.x;
    const int b  = blk / 36;
    const int r  = blk - b*36;
    const int o0 = r >> 2;
    const int tt = r & 3;
    const int o1b = tt*2;                 // 0,2,4,6
    const bool ragged = (tt == 3);        // o1 pair {6,-}: second row invalid
    const int tid = threadIdx.x;

    // ---- stage slab: 3 k0-planes x 4 d1-rows, packed bf16 pairs ----
    const size_t ibase = (size_t)b*IN_PER_B + (size_t)o0*PLANE + (size_t)o1b*ROWW;
    const int cpyv = ragged ? 3*ROWW : SEG;   // ragged: d1 row 9 doesn't exist -> zero
    for (int k0 = 0; k0 < 3; ++k0) {
        const float* gr = x_re + ibase + (size_t)k0*PLANE;
        const float* gi = x_im + ibase + (size_t)k0*PLANE;
        unsigned* ds = sx + k0*SEG;
        for (int i = tid; i < SEG; i += 256) {
            unsigned v = 0;
            if (i < cpyv) v = packpair(gr[i], gi[i]);
            ds[i] = v;
        }
    }

    // ---- per-lane A-fragments + row offsets ----
    const int lane = tid & 63;
    const int m  = lane & 15;
    const int kb = lane >> 4;
    const int ch = m & 3;
    const bool isIm = (m & 4) != 0;
    const int o1ofs = m >> 3;

    short8 afrag[9];
    int rowoff[9];
    #pragma unroll
    for (int c = 0; c < 9; ++c) {
        const int j = 4*c + kb;               // K-row 0..35: (k0, d1local, k2)
        const int k0 = j / 12;
        const int rm = j - k0*12;
        const int d1l = rm / 3;
        const int k2 = rm - d1l*3;
        rowoff[c] = k0*SEG + d1l*ROWW + k2*39;
        short8 a = {0,0,0,0,0,0,0,0};
        const int k1 = d1l - o1ofs;
        if (k1 >= 0 && k1 < 3 && !(ragged && o1ofs)) {
            #pragma unroll
            for (int s = 0; s < 3; ++s) {
                const int tp = ch*81 + k0*27 + k1*9 + k2*3 + s;
                const float wr = w_re[tp];
                const float wi = w_im[tp];
                a[2*s]   = bf16s(isIm ? wi : wr);   // multiplies xr
                a[2*s+1] = bf16s(isIm ? wr : -wi);  // multiplies xi
            }
        }
        afrag[c] = a;
    }
    float brv[4], biv[4];
    #pragma unroll
    for (int c2 = 0; c2 < 4; ++c2) { brv[c2] = b_re[c2]; biv[c2] = b_im[c2]; }
    __syncthreads();

    // ---- tile loop: 31 tiles of 16 positions cover 481; each tile = 32 outputs ----
    const int wave = tid >> 6;
    const int fbase = (o0*7 + o1b)*POSPP;
    float partial = 0.f;

    for (int tile = wave; tile < 31; tile += 4) {
        const int n = tile*16 + m;
        const bool ok = n < POSPP;
        const int p = ok ? n : 0;
        const int o2 = p / 37;                // only divide left (magic-mul)
        const int pb = p + 2*o2;              // o2*39 + o3

        f32x4 acc = {0.f, 0.f, 0.f, 0.f};
        #pragma unroll
        for (int c = 0; c < 9; ++c) {
            const unsigned* s = sx + pb + rowoff[c];
            union { unsigned u[4]; short8 s8; } bu;
            bu.u[0] = s[0];
            bu.u[1] = s[1];
            bu.u[2] = s[2];
            bu.u[3] = bu.u[2];                // pad slot, zero-weighted (in-bounds dup)
            acc = __builtin_amdgcn_mfma_f32_16x16x32_bf16(afrag[c], bu.s8, acc, 0, 0, 0);
        }

        // pair re (groups 0,2) with im (groups 1,3) via +16 shuffle
        float imv[4];
        #pragma unroll
        for (int c2 = 0; c2 < 4; ++c2) imv[c2] = __shfl_down(acc[c2], 16, 64);
        if (((lane & 16) == 0) && ok && (lane < 16 || !ragged)) {
            const int fb = fbase + p + ((lane >= 32) ? POSPP : 0);
            #pragma unroll
            for (int c2 = 0; c2 < 4; ++c2) {
                const float re = fmaxf(acc[c2] + brv[c2], 0.f);
                const float im = fmaxf(imv[c2] + biv[c2], 0.f);
                partial += sqrtf(fmaf(re, re, im*im)) * lw[c2*OUT_SP + fb];
            }
        }
    }

    // wave reduce then block reduce; one plain store per block (no atomics/memset)
    #pragma unroll
    for (int off = 32; off > 0; off >>= 1)
        partial += __shfl_down(partial, off, 64);
    if ((tid & 63) == 0) red[tid >> 6] = partial;
    __syncthreads();
    if (tid == 0) partials[blk] = red[0] + red[1] + red[2] + red[3];
}

__global__ void finalize_k(const float* __restrict__ part, const float* __restrict__ lb,
                           float* __restrict__ out) {
    const int i = blockIdx.x * blockDim.x + threadIdx.x;
    if (i < NB) {
        float s = 0.f;
        #pragma unroll
        for (int j = 0; j < 36; ++j) s += part[i*36 + j];
        out[i] = 1.f / (1.f + expf(-(s + lb[0])));
    }
}

extern "C" void kernel_launch(void* const* d_in, const int* in_sizes, int n_in,
                              void* d_out, int out_size, void* d_ws, size_t ws_size,
                              hipStream_t stream) {
    const float* x_re = (const float*)d_in[0];
    const float* x_im = (const float*)d_in[1];
    const float* w_re = (const float*)d_in[2];
    const float* w_im = (const float*)d_in[3];
    const float* b_re = (const float*)d_in[4];
    const float* b_im = (const float*)d_in[5];
    const float* lw   = (const float*)d_in[6];
    const float* lb   = (const float*)d_in[7];
    float* partials = (float*)d_ws;   // 512*36 floats; every slot written per launch

    hipLaunchKernelGGL(conv_mfma, dim3(NB*36), dim3(256), 0, stream,
                       x_re, x_im, w_re, w_im, b_re, b_im, lw, partials);
    finalize_k<<<dim3(2), dim3(256), 0, stream>>>(partials, lb, (float*)d_out);
}

// Round 9
// 398.019 us; speedup vs baseline: 2.5095x; 1.3931x over previous
//
#include <hip/hip_runtime.h>
#include <hip/hip_bf16.h>
#include <math.h>

#define NB 512
#define ROWW 585            // 15*39
#define PLANE 5265          // 9*15*39
#define IN_PER_B 57915      // 11*9*15*39
#define OUT_SP 30303        // 9*7*13*37
#define SEG 2340            // LDS k0-plane stride: 4 d1-rows * 585 (u32 pairs)
#define POSPP 481           // 13*37 positions per o1-row

typedef __attribute__((ext_vector_type(8))) short short8;   // 8 bf16 = 4 VGPR
typedef __attribute__((ext_vector_type(4))) float f32x4;
typedef float f4u __attribute__((ext_vector_type(4), aligned(4)));  // 4B-aligned float4

__device__ __forceinline__ unsigned bf16rne(float f) {
    unsigned u = __float_as_uint(f);
    return (u + 0x7fffu + ((u >> 16) & 1u)) >> 16;
}
__device__ __forceinline__ short bf16s(float f) { return (short)bf16rne(f); }

__device__ __forceinline__ unsigned packpair(float re, float im) {
    __hip_bfloat162 h = __float22bfloat162_rn(make_float2(re, im));  // v_cvt_pk_bf16_f32
    union { __hip_bfloat162 h2; unsigned u; } cv; cv.h2 = h;
    return cv.u;   // low16 = re, high16 = im
}

// Pre-kernel: per-lane A-fragments (weights) for both ragged variants.
// tab[rg][c][lane], entry = short8. Same math as R8's in-kernel build (verified).
__global__ void build_afrag(const float* __restrict__ w_re, const float* __restrict__ w_im,
                            short8* __restrict__ tab) {
    const int e = blockIdx.x * blockDim.x + threadIdx.x;   // 0..1151
    if (e >= 2*9*64) return;
    const int lane = e & 63;
    const int c    = (e >> 6) % 9;
    const int rg   = e / (9*64);
    const int m  = lane & 15;
    const int kb = lane >> 4;
    const int ch = m & 3;
    const bool isIm = (m & 4) != 0;
    const int o1ofs = m >> 3;
    const int j  = 4*c + kb;              // K-row 0..35: (k0, d1local, k2)
    const int k0 = j / 12;
    const int rm = j - k0*12;
    const int d1l = rm / 3;
    const int k2  = rm - d1l*3;
    const int k1  = d1l - o1ofs;
    short8 a = {0,0,0,0,0,0,0,0};
    if (k1 >= 0 && k1 < 3 && !(rg && o1ofs)) {
        #pragma unroll
        for (int s = 0; s < 3; ++s) {
            const int tp = ch*81 + k0*27 + k1*9 + k2*3 + s;
            const float wr = w_re[tp];
            const float wi = w_im[tp];
            a[2*s]   = bf16s(isIm ? wi : wr);   // multiplies xr
            a[2*s+1] = bf16s(isIm ? wr : -wi);  // multiplies xi
        }
    }
    tab[e] = a;
}

// Complex 4D conv as MFMA GEMM, dual o1-row per tile (R8-verified mapping):
// C[16][16pos]: rows 0-3 re(o1l) ch0-3, 4-7 im(o1l), 8-11 re(o1l+1), 12-15 im(o1l+1).
// K = 36 rows x 4 slots{k3=0,1,2,pad} x {xr,xi} = 288 = 9 MFMA chunks.
// B-frag = 4 CONTIGUOUS u32 (pad slot reads next elem, zero-weighted; slab +4 pad).
__global__ __launch_bounds__(256, 5) void conv_mfma(
    const float* __restrict__ x_re, const float* __restrict__ x_im,
    const float* __restrict__ b_re, const float* __restrict__ b_im,
    const float* __restrict__ lw, const short8* __restrict__ tab,
    float* __restrict__ partials)
{
    __shared__ unsigned sx[3*SEG + 4];   // 28.2 KB packed bf16 (re|im) pairs + pad
    __shared__ float red[4];

    const int blk = blockIdx.x;
    const int b  = blk / 36;
    const int r  = blk - b*36;
    const int o0 = r >> 2;
    const int tt = r & 3;
    const int o1b = tt*2;                 // 0,2,4,6
    const bool ragged = (tt == 3);        // o1 pair {6,-}: second row invalid
    const int tid = threadIdx.x;
    const int lane = tid & 63;

    // ---- A-fragments from table: 9x global_load_dwordx4, issued first ----
    short8 afrag[9];
    {
        const short8* tp = tab + (ragged ? 9*64 : 0) + lane;
        #pragma unroll
        for (int c = 0; c < 9; ++c) afrag[c] = tp[c*64];
    }

    // ---- stage slab: float4 loads (4B-aligned ok), cvt_pk, ds_write_b128 ----
    const size_t ibase = (size_t)b*IN_PER_B + (size_t)o0*PLANE + (size_t)o1b*ROWW;
    const int cpyv = ragged ? 3*ROWW : SEG;   // ragged: 4th d1-row absent -> zeros
    for (int k0 = 0; k0 < 3; ++k0) {
        const f4u* gr = (const f4u*)(x_re + ibase + (size_t)k0*PLANE);
        const f4u* gi = (const f4u*)(x_im + ibase + (size_t)k0*PLANE);
        uint4* ds = (uint4*)(sx + k0*SEG);
        for (int i = tid; i < SEG/4; i += 256) {
            const f4u vr = gr[i];
            const f4u vi = gi[i];
            uint4 w;
            w.x = (4*i+0 < cpyv) ? packpair(vr.x, vi.x) : 0u;
            w.y = (4*i+1 < cpyv) ? packpair(vr.y, vi.y) : 0u;
            w.z = (4*i+2 < cpyv) ? packpair(vr.z, vi.z) : 0u;
            w.w = (4*i+3 < cpyv) ? packpair(vr.w, vi.w) : 0u;
            ds[i] = w;
        }
    }
    if (tid < 4) sx[3*SEG + tid] = 0;     // pad: B-frag 4th slot may land here

    // ---- per-lane row offsets ----
    const int m  = lane & 15;
    const int kb = lane >> 4;
    int rowoff[9];
    #pragma unroll
    for (int c = 0; c < 9; ++c) {
        const int j = 4*c + kb;
        const int k0 = j / 12;
        const int rm = j - k0*12;
        const int d1l = rm / 3;
        const int k2 = rm - d1l*3;
        rowoff[c] = k0*SEG + d1l*ROWW + k2*39;
    }

    // tile-invariant epilogue constants (bias/lw per lane's 2 channels)
    const bool hig = (lane & 16) != 0;            // channel group: 0,1 vs 2,3
    const float bre0 = hig ? b_re[2] : b_re[0];
    const float bim0 = hig ? b_im[2] : b_im[0];
    const float bre1 = hig ? b_re[3] : b_re[1];
    const float bim1 = hig ? b_im[3] : b_im[1];
    const float* lw0 = lw + (hig ? 2*OUT_SP : 0);
    const float* lw1 = lw0 + OUT_SP;
    const int fbase = (o0*7 + o1b)*POSPP + ((lane >= 32) ? POSPP : 0);
    const bool lactive = (lane < 32) || !ragged;  // upper o1-row invalid when ragged

    __syncthreads();

    const int wave = tid >> 6;
    float partial = 0.f;

    auto do_tile = [&](int tile) {
        const int n = tile*16 + m;
        const bool ok = (n < POSPP) && lactive;
        const int p = (n < POSPP) ? n : 0;
        const int o2 = p / 37;
        const int pb = p + 2*o2;              // p + o2*2 == o2*39 + o3

        f32x4 acc = {0.f, 0.f, 0.f, 0.f};
        #pragma unroll
        for (int c = 0; c < 9; ++c) {
            const unsigned* s = sx + pb + rowoff[c];
            union { unsigned u[4]; short8 s8; } bu;
            bu.u[0] = s[0]; bu.u[1] = s[1]; bu.u[2] = s[2]; bu.u[3] = s[3];
            acc = __builtin_amdgcn_mfma_f32_16x16x32_bf16(afrag[c], bu.s8, acc, 0, 0, 0);
        }

        // partner exchange: re rows <-> im rows live 16 lanes apart
        float ex[4];
        #pragma unroll
        for (int c2 = 0; c2 < 4; ++c2) ex[c2] = __shfl_xor(acc[c2], 16, 64);

        if (ok) {
            // g0 lanes: ch {0,1}: re=own, im=partner. g1 lanes: ch {2,3}: re=partner, im=own.
            const float r0 = hig ? ex[2]  : acc[0];
            const float i0 = hig ? acc[2] : ex[0];
            const float r1 = hig ? ex[3]  : acc[1];
            const float i1 = hig ? acc[3] : ex[1];
            const int fb = fbase + p;
            const float re0 = fmaxf(r0 + bre0, 0.f), im0 = fmaxf(i0 + bim0, 0.f);
            const float re1 = fmaxf(r1 + bre1, 0.f), im1 = fmaxf(i1 + bim1, 0.f);
            partial += sqrtf(fmaf(re0, re0, im0*im0)) * lw0[fb];
            partial += sqrtf(fmaf(re1, re1, im1*im1)) * lw1[fb];
        }
    };

    // 2 tiles in flight per wave: waves get pairs {2w,2w+1} stride 8 over 31 tiles
    for (int t = wave*2; t < 31; t += 8) {
        do_tile(t);
        if (t + 1 < 31) do_tile(t + 1);
    }

    // wave reduce then block reduce; one plain store per block
    #pragma unroll
    for (int off = 32; off > 0; off >>= 1)
        partial += __shfl_down(partial, off, 64);
    if ((tid & 63) == 0) red[tid >> 6] = partial;
    __syncthreads();
    if (tid == 0) partials[blk] = red[0] + red[1] + red[2] + red[3];
}

__global__ void finalize_k(const float* __restrict__ part, const float* __restrict__ lb,
                           float* __restrict__ out) {
    const int i = blockIdx.x * blockDim.x + threadIdx.x;
    if (i < NB) {
        float s = 0.f;
        #pragma unroll
        for (int j = 0; j < 36; ++j) s += part[i*36 + j];
        out[i] = 1.f / (1.f + expf(-(s + lb[0])));
    }
}

extern "C" void kernel_launch(void* const* d_in, const int* in_sizes, int n_in,
                              void* d_out, int out_size, void* d_ws, size_t ws_size,
                              hipStream_t stream) {
    const float* x_re = (const float*)d_in[0];
    const float* x_im = (const float*)d_in[1];
    const float* w_re = (const float*)d_in[2];
    const float* w_im = (const float*)d_in[3];
    const float* b_re = (const float*)d_in[4];
    const float* b_im = (const float*)d_in[5];
    const float* lw   = (const float*)d_in[6];
    const float* lb   = (const float*)d_in[7];

    float* partials = (float*)d_ws;                          // 512*36 floats
    short8* tab = (short8*)((char*)d_ws + NB*36*sizeof(float)); // 2*9*64 short8 (18KB)

    build_afrag<<<dim3(5), dim3(256), 0, stream>>>(w_re, w_im, tab);
    hipLaunchKernelGGL(conv_mfma, dim3(NB*36), dim3(256), 0, stream,
                       x_re, x_im, b_re, b_im, lw, tab, partials);
    finalize_k<<<dim3(2), dim3(256), 0, stream>>>(partials, lb, (float*)d_out);
}